// Round 1
// baseline (1887.122 us; speedup 1.0000x reference)
//
#include <hip/hip_runtime.h>
#include <hip/hip_bf16.h>
#include <math.h>

typedef __bf16 bf16;
typedef __attribute__((ext_vector_type(4))) __bf16 bf16x4;
typedef __attribute__((ext_vector_type(8))) __bf16 bf16x8;
typedef __attribute__((ext_vector_type(4))) float floatx4;

#define NTOK 4096
#define DM 1024
#define DF 4096
#define NE 16
#define NPAIR 8192

// ---------------- ws layout (bytes) ----------------
static const size_t OFF_W1Q = 0ull;                     // bf16 [16][4096][1024]  134217728
static const size_t OFF_W2Q = 134217728ull;             // bf16 [16][1024][4096]  134217728
static const size_t OFF_AQ  = 268435456ull;             // bf16 [8192+128][1024]   17039360
static const size_t OFF_HQ  = 285474816ull;             // bf16 [8192+128][4096]   68157440
static const size_t OFF_H   = 353632256ull;             // f32  [8192][4096]      134217728
static const size_t OFF_S   = 487849984ull;             // small arrays
static const size_t S_CNT   = OFF_S + 0;       // 16 i32
static const size_t S_FILL  = OFF_S + 256;     // 16 i32
static const size_t S_PSUM  = OFF_S + 512;     // 16 f32
static const size_t S_OFFS  = OFF_S + 768;     // 17 i32
static const size_t S_MW    = OFF_S + 1024;    // 32 f32 (0..15 w1, 16..31 w2)
static const size_t S_INVMW = OFF_S + 1280;    // 32 f32
static const size_t S_PART  = OFF_S + 1536;    // 1024 f32
static const size_t S_TOPI  = OFF_S + 8192;    // 4096*2 i32
static const size_t S_TOPP  = OFF_S + 40960;   // 4096*2 f32
static const size_t S_STOK  = OFF_S + 73728;   // 8192 i32
static const size_t S_SEXP  = OFF_S + 106496;  // 8192 i32
static const size_t S_SW    = OFF_S + 139264;  // 8192 f32
static const size_t S_ISA   = OFF_S + 172032;  // 8192 f32
static const size_t S_ISB   = OFF_S + 204800;  // 8192 f32
static const size_t WS_REQUIRED = OFF_S + 237568ull;    // ~488.1 MB

// ---------------- helpers ----------------
__device__ __forceinline__ float wave_sum(float v) {
#pragma unroll
    for (int o = 32; o; o >>= 1) v += __shfl_xor(v, o, 64);
    return v;
}
__device__ __forceinline__ float wave_max(float v) {
#pragma unroll
    for (int o = 32; o; o >>= 1) v = fmaxf(v, __shfl_xor(v, o, 64));
    return v;
}
__device__ __forceinline__ float gelu_tanh(float v) {
    // jax.nn.gelu approximate=True (tanh form)
    float u = 0.7978845608028654f * (v + 0.044715f * v * v * v);
    return 0.5f * v * (1.0f + tanhf(u));
}

__global__ void ksentinel(float* out) { out[0] = 1.0e30f; }  // ws too small marker

// ---------------- router: logits, softmax, top2, counts, p-sums ----------------
__global__ __launch_bounds__(64) void router_kernel(
    const float* __restrict__ x, const float* __restrict__ rw,
    int* __restrict__ topi, float* __restrict__ topp,
    int* __restrict__ cnt, float* __restrict__ psum)
{
    const int n = blockIdx.x;
    const int lane = threadIdx.x;
    const float* xr = x + (size_t)n * DM;
    float acc[16];
#pragma unroll
    for (int e = 0; e < 16; e++) acc[e] = 0.f;
    for (int i = 0; i < 16; i++) {
        const float xv = xr[i * 64 + lane];
#pragma unroll
        for (int e = 0; e < 16; e++) acc[e] += xv * rw[e * DM + i * 64 + lane];
    }
#pragma unroll
    for (int e = 0; e < 16; e++) acc[e] = wave_sum(acc[e]);
    float mx = acc[0];
#pragma unroll
    for (int e = 1; e < 16; e++) mx = fmaxf(mx, acc[e]);
    float p[16]; float den = 0.f;
#pragma unroll
    for (int e = 0; e < 16; e++) { p[e] = expf(acc[e] - mx); den += p[e]; }
    const float invden = 1.0f / den;
#pragma unroll
    for (int e = 0; e < 16; e++) p[e] *= invden;
    // top-2, earliest index wins ties (matches lax.top_k)
    float b0 = -1.f; int i0 = 0;
#pragma unroll
    for (int e = 0; e < 16; e++) { if (p[e] > b0) { b0 = p[e]; i0 = e; } }
    float b1 = -1.f; int i1 = 0;
#pragma unroll
    for (int e = 0; e < 16; e++) { if (e != i0 && p[e] > b1) { b1 = p[e]; i1 = e; } }
    const float s = b0 + b1 + 1e-8f;
    if (lane == 0) {
        topi[2 * n] = i0; topi[2 * n + 1] = i1;
        topp[2 * n] = b0 / s; topp[2 * n + 1] = b1 / s;
        atomicAdd(&cnt[i0], 1); atomicAdd(&cnt[i1], 1);
#pragma unroll
        for (int e = 0; e < 16; e++) atomicAdd(&psum[e], p[e]);
    }
}

// ---------------- prefix offsets + aux loss ----------------
__global__ void kpfx_kernel(const int* __restrict__ cnt, const float* __restrict__ psum,
                            int* __restrict__ offs, float* __restrict__ aux_out)
{
    if (threadIdx.x == 0 && blockIdx.x == 0) {
        int o = 0; float aux = 0.f;
        for (int e = 0; e < 16; e++) {
            offs[e] = o; o += cnt[e];
            aux += ((float)cnt[e] * (1.0f / 8192.0f)) * (psum[e] * (1.0f / 4096.0f));
        }
        offs[16] = o;
        *aux_out = 16.0f * aux;
    }
}

// ---------------- fill compacted per-expert slot lists ----------------
__global__ __launch_bounds__(256) void kfill_kernel(
    const int* __restrict__ topi, const float* __restrict__ topp,
    const int* __restrict__ offs, int* __restrict__ fill,
    int* __restrict__ stok, int* __restrict__ sexp, float* __restrict__ sw)
{
    const int n = blockIdx.x * 256 + threadIdx.x;
    if (n >= NTOK) return;
#pragma unroll
    for (int k = 0; k < 2; k++) {
        const int e = topi[2 * n + k];
        const int pos = atomicAdd(&fill[e], 1);
        const int slot = offs[e] + pos;
        stok[slot] = n; sexp[slot] = e; sw[slot] = topp[2 * n + k];
    }
}

// ---------------- weight mean|w| partial reduce ----------------
__global__ __launch_bounds__(256) void kwsum_kernel(
    const float* __restrict__ w1, const float* __restrict__ w2, float* __restrict__ partial)
{
    const int b = blockIdx.x;                 // 1024 blocks: mat(1b) | e(4b) | chunk(5b)
    const int mat = b >> 9, e = (b >> 5) & 15, chunk = b & 31;
    const float4* w4 = (const float4*)((mat ? w2 : w1) + (size_t)e * 4194304ull + (size_t)chunk * 131072ull);
    const int tid = threadIdx.x;
    float s = 0.f;
    for (int i = 0; i < 128; i++) {
        float4 v = w4[i * 256 + tid];
        s += fabsf(v.x) + fabsf(v.y) + fabsf(v.z) + fabsf(v.w);
    }
    s = wave_sum(s);
    __shared__ float red[4];
    if ((tid & 63) == 0) red[tid >> 6] = s;
    __syncthreads();
    if (tid == 0) partial[b] = red[0] + red[1] + red[2] + red[3];
}

__global__ void kwscale_kernel(const float* __restrict__ partial,
                               float* __restrict__ mw, float* __restrict__ inv_mw)
{
    const int me = threadIdx.x;
    if (me < 32) {
        float s = 0.f;
        for (int c = 0; c < 32; c++) s += partial[me * 32 + c];
        const float mean = s * (1.0f / 4194304.0f);
        const float cm = fmaxf(mean, 1e-5f);
        mw[me] = cm;
        inv_mw[me] = 1.0f / cm;
    }
}

// ---------------- ternarize weights -> bf16 ----------------
__global__ __launch_bounds__(256) void kwquant_kernel(
    const float* __restrict__ w1, const float* __restrict__ w2,
    const float* __restrict__ inv_mw, bf16* __restrict__ w1q, bf16* __restrict__ w2q)
{
    const long long i = (long long)blockIdx.x * 256 + threadIdx.x;  // float4 index
    const int mat = i >= 16777216ll;
    const long long j = mat ? i - 16777216ll : i;
    const int e = (int)(j >> 20);
    const float inv = inv_mw[mat * 16 + e];
    const float4 v = ((const float4*)(mat ? w2 : w1))[j];
    bf16x4 q;
    q.x = (bf16)fminf(fmaxf(rintf(v.x * inv), -1.f), 1.f);
    q.y = (bf16)fminf(fmaxf(rintf(v.y * inv), -1.f), 1.f);
    q.z = (bf16)fminf(fmaxf(rintf(v.z * inv), -1.f), 1.f);
    q.w = (bf16)fminf(fmaxf(rintf(v.w * inv), -1.f), 1.f);
    ((bf16x4*)(mat ? w2q : w1q))[j] = q;
}

// ---------------- per-pair rmsnorm + act quant (x -> aq) ----------------
__global__ __launch_bounds__(64) void kaq_kernel(
    const float* __restrict__ x, const float* __restrict__ g1,
    const int* __restrict__ stok, const int* __restrict__ sexp,
    bf16* __restrict__ aq, float* __restrict__ inv_sa)
{
    const int slot = blockIdx.x;
    const int lane = threadIdx.x;
    const int tok = stok[slot], e = sexp[slot];
    const float4* xr = (const float4*)(x + (size_t)tok * DM);
    const float4* gr = (const float4*)(g1 + (size_t)e * DM);
    float4 xv[4]; float ss = 0.f;
#pragma unroll
    for (int i = 0; i < 4; i++) {
        xv[i] = xr[i * 64 + lane];
        ss += xv[i].x * xv[i].x + xv[i].y * xv[i].y + xv[i].z * xv[i].z + xv[i].w * xv[i].w;
    }
    ss = wave_sum(ss);
    const float rsq = rsqrtf(ss * (1.0f / DM) + 1e-6f);
    float4 xn[4]; float am = 0.f;
#pragma unroll
    for (int i = 0; i < 4; i++) {
        float4 g = gr[i * 64 + lane];
        xn[i].x = xv[i].x * g.x * rsq; xn[i].y = xv[i].y * g.y * rsq;
        xn[i].z = xv[i].z * g.z * rsq; xn[i].w = xv[i].w * g.w * rsq;
        am = fmaxf(am, fmaxf(fmaxf(fabsf(xn[i].x), fabsf(xn[i].y)),
                             fmaxf(fabsf(xn[i].z), fabsf(xn[i].w))));
    }
    am = wave_max(am);
    const float cm = fmaxf(am, 1e-5f);
    const float sc = 127.0f / cm;
    bf16x4* ar = (bf16x4*)(aq + (size_t)slot * DM);
#pragma unroll
    for (int i = 0; i < 4; i++) {
        bf16x4 q;
        q.x = (bf16)fminf(fmaxf(rintf(xn[i].x * sc), -128.f), 127.f);
        q.y = (bf16)fminf(fmaxf(rintf(xn[i].y * sc), -128.f), 127.f);
        q.z = (bf16)fminf(fmaxf(rintf(xn[i].z * sc), -128.f), 127.f);
        q.w = (bf16)fminf(fmaxf(rintf(xn[i].w * sc), -128.f), 127.f);
        ar[i * 64 + lane] = q;
    }
    if (lane == 0) inv_sa[slot] = cm / 127.0f;
}

// ---------------- h rmsnorm + act quant (h -> hq) ----------------
__global__ __launch_bounds__(256) void khq_kernel(
    const float* __restrict__ h, const float* __restrict__ g2,
    const int* __restrict__ sexp, bf16* __restrict__ hq, float* __restrict__ inv_sb)
{
    const int slot = blockIdx.x;
    const int tid = threadIdx.x;
    const int wave = tid >> 6, lane = tid & 63;
    const int e = sexp[slot];
    const float4* hr = (const float4*)(h + (size_t)slot * DF);
    const float4* gr = (const float4*)(g2 + (size_t)e * DF);
    __shared__ float red[4];
    float4 hv[4]; float ss = 0.f;
#pragma unroll
    for (int i = 0; i < 4; i++) {
        hv[i] = hr[i * 256 + tid];
        ss += hv[i].x * hv[i].x + hv[i].y * hv[i].y + hv[i].z * hv[i].z + hv[i].w * hv[i].w;
    }
    ss = wave_sum(ss);
    if (lane == 0) red[wave] = ss;
    __syncthreads();
    ss = red[0] + red[1] + red[2] + red[3];
    const float rsq = rsqrtf(ss * (1.0f / DF) + 1e-6f);
    float4 tn[4]; float am = 0.f;
#pragma unroll
    for (int i = 0; i < 4; i++) {
        float4 g = gr[i * 256 + tid];
        tn[i].x = hv[i].x * g.x * rsq; tn[i].y = hv[i].y * g.y * rsq;
        tn[i].z = hv[i].z * g.z * rsq; tn[i].w = hv[i].w * g.w * rsq;
        am = fmaxf(am, fmaxf(fmaxf(fabsf(tn[i].x), fabsf(tn[i].y)),
                             fmaxf(fabsf(tn[i].z), fabsf(tn[i].w))));
    }
    am = wave_max(am);
    __syncthreads();
    if (lane == 0) red[wave] = am;
    __syncthreads();
    am = fmaxf(fmaxf(red[0], red[1]), fmaxf(red[2], red[3]));
    const float cm = fmaxf(am, 1e-5f);
    const float sc = 127.0f / cm;
    bf16x4* orow = (bf16x4*)(hq + (size_t)slot * DF);
#pragma unroll
    for (int i = 0; i < 4; i++) {
        bf16x4 q;
        q.x = (bf16)fminf(fmaxf(rintf(tn[i].x * sc), -128.f), 127.f);
        q.y = (bf16)fminf(fmaxf(rintf(tn[i].y * sc), -128.f), 127.f);
        q.z = (bf16)fminf(fmaxf(rintf(tn[i].z * sc), -128.f), 127.f);
        q.w = (bf16)fminf(fmaxf(rintf(tn[i].w * sc), -128.f), 127.f);
        orow[i * 256 + tid] = q;
    }
    if (tid == 0) inv_sb[slot] = cm / 127.0f;
}

// ---------------- MFMA mainloop: 128x128 tile, BK=64, 4 waves of 64x64 ----------------
// A layout in LDS: [row 0..127][k 0..63], stride 72 (144B: 16B-aligned, <=2-way banks)
__device__ __forceinline__ void gemm_mainloop(
    const bf16* __restrict__ Ab, const bf16* __restrict__ Bb,
    const int kdim, bf16* As, bf16* Bs, floatx4 acc[4][4])
{
    const int tid = threadIdx.x;
    const int wave = tid >> 6, lane = tid & 63;
    const int wr = (wave >> 1) * 64, wc = (wave & 1) * 64;
    const int quad = lane >> 4, l16 = lane & 15;
    const int sr = tid >> 1, sh = (tid & 1) * 32;
    const float4* gA = (const float4*)(Ab + (size_t)sr * kdim + sh);
    const float4* gB = (const float4*)(Bb + (size_t)sr * kdim + sh);
    float4* lA = (float4*)(As + sr * 72 + sh);
    float4* lB = (float4*)(Bs + sr * 72 + sh);
    const int kIters = kdim >> 6;
    for (int ki = 0; ki < kIters; ++ki) {
        __syncthreads();
        float4 a0 = gA[0], a1 = gA[1], a2 = gA[2], a3 = gA[3];
        float4 b0 = gB[0], b1 = gB[1], b2 = gB[2], b3 = gB[3];
        gA += 8; gB += 8;
        lA[0] = a0; lA[1] = a1; lA[2] = a2; lA[3] = a3;
        lB[0] = b0; lB[1] = b1; lB[2] = b2; lB[3] = b3;
        __syncthreads();
#pragma unroll
        for (int kk = 0; kk < 64; kk += 32) {
            bf16x8 af[4], bfm[4];
#pragma unroll
            for (int i = 0; i < 4; i++)
                af[i] = *(const bf16x8*)(As + (wr + 16 * i + l16) * 72 + kk + quad * 8);
#pragma unroll
            for (int j = 0; j < 4; j++)
                bfm[j] = *(const bf16x8*)(Bs + (wc + 16 * j + l16) * 72 + kk + quad * 8);
#pragma unroll
            for (int i = 0; i < 4; i++)
#pragma unroll
                for (int j = 0; j < 4; j++)
                    acc[i][j] = __builtin_amdgcn_mfma_f32_16x16x32_bf16(af[i], bfm[j], acc[i][j], 0, 0, 0);
        }
    }
}

// ---------------- GEMM1: h_int = aq @ w1q^T ; epilogue scale+gelu -> h ----------------
__global__ __launch_bounds__(256) void gemm1_kernel(
    const bf16* __restrict__ aq, const bf16* __restrict__ w1q,
    const int* __restrict__ cnt, const int* __restrict__ offs,
    const float* __restrict__ inv_sa, const float* __restrict__ mw,
    float* __restrict__ h)
{
    const int e = blockIdx.z;
    const int ce = cnt[e];
    const int m0 = blockIdx.y * 128;
    if (m0 >= ce) return;
    const int n0 = blockIdx.x * 128;
    const int off = offs[e];
    __shared__ bf16 As[128 * 72];
    __shared__ bf16 Bs[128 * 72];
    floatx4 acc[4][4];
#pragma unroll
    for (int i = 0; i < 4; i++)
#pragma unroll
        for (int j = 0; j < 4; j++) { floatx4 z = {0.f, 0.f, 0.f, 0.f}; acc[i][j] = z; }
    gemm_mainloop(aq + (size_t)(off + m0) * DM, w1q + ((size_t)e * DF + n0) * DM, DM, As, Bs, acc);
    const int tid = threadIdx.x, wave = tid >> 6, lane = tid & 63;
    const int wr = (wave >> 1) * 64, wc = (wave & 1) * 64, quad = lane >> 4, l16 = lane & 15;
    const float sm = mw[e];
#pragma unroll
    for (int i = 0; i < 4; i++) {
#pragma unroll
        for (int r = 0; r < 4; r++) {
            const int ml = wr + 16 * i + quad * 4 + r;
            if (m0 + ml < ce) {
                const int slot = off + m0 + ml;
                const float sc = sm * inv_sa[slot];
                float* hrow = h + (size_t)slot * DF + n0 + wc + l16;
#pragma unroll
                for (int j = 0; j < 4; j++) hrow[16 * j] = gelu_tanh(acc[i][j][r] * sc);
            }
        }
    }
}

// ---------------- GEMM2: o_int = hq @ w2q^T ; epilogue scale*pairweight, atomic scatter ----------------
__global__ __launch_bounds__(256) void gemm2_kernel(
    const bf16* __restrict__ hq, const bf16* __restrict__ w2q,
    const int* __restrict__ cnt, const int* __restrict__ offs,
    const float* __restrict__ inv_sb, const float* __restrict__ sw,
    const int* __restrict__ stok, const float* __restrict__ mw,
    float* __restrict__ out)
{
    const int e = blockIdx.z;
    const int ce = cnt[e];
    const int m0 = blockIdx.y * 128;
    if (m0 >= ce) return;
    const int n0 = blockIdx.x * 128;
    const int off = offs[e];
    __shared__ bf16 As[128 * 72];
    __shared__ bf16 Bs[128 * 72];
    floatx4 acc[4][4];
#pragma unroll
    for (int i = 0; i < 4; i++)
#pragma unroll
        for (int j = 0; j < 4; j++) { floatx4 z = {0.f, 0.f, 0.f, 0.f}; acc[i][j] = z; }
    gemm_mainloop(hq + (size_t)(off + m0) * DF, w2q + ((size_t)e * DM + n0) * DF, DF, As, Bs, acc);
    const int tid = threadIdx.x, wave = tid >> 6, lane = tid & 63;
    const int wr = (wave >> 1) * 64, wc = (wave & 1) * 64, quad = lane >> 4, l16 = lane & 15;
    const float sm = mw[16 + e];
#pragma unroll
    for (int i = 0; i < 4; i++) {
#pragma unroll
        for (int r = 0; r < 4; r++) {
            const int ml = wr + 16 * i + quad * 4 + r;
            if (m0 + ml < ce) {
                const int slot = off + m0 + ml;
                const float sc = sm * inv_sb[slot] * sw[slot];
                const int tok = stok[slot];
                float* orow = out + (size_t)tok * DM + n0 + wc + l16;
#pragma unroll
                for (int j = 0; j < 4; j++) atomicAdd(&orow[16 * j], acc[i][j][r] * sc);
            }
        }
    }
}

// ---------------- launcher ----------------
extern "C" void kernel_launch(void* const* d_in, const int* in_sizes, int n_in,
                              void* d_out, int out_size, void* d_ws, size_t ws_size,
                              hipStream_t stream)
{
    const float* x  = (const float*)d_in[0];
    const float* rw = (const float*)d_in[1];
    const float* w1 = (const float*)d_in[2];
    const float* g1 = (const float*)d_in[3];
    const float* w2 = (const float*)d_in[4];
    const float* g2 = (const float*)d_in[5];
    float* out = (float*)d_out;
    char* ws = (char*)d_ws;

    if (ws_size < WS_REQUIRED) {
        ksentinel<<<1, 1, 0, stream>>>(out);
        return;
    }

    bf16*  w1q   = (bf16*)(ws + OFF_W1Q);
    bf16*  w2q   = (bf16*)(ws + OFF_W2Q);
    bf16*  aq    = (bf16*)(ws + OFF_AQ);
    bf16*  hq    = (bf16*)(ws + OFF_HQ);
    float* h     = (float*)(ws + OFF_H);
    int*   cnt   = (int*)(ws + S_CNT);
    int*   fill  = (int*)(ws + S_FILL);
    float* psum  = (float*)(ws + S_PSUM);
    int*   offs  = (int*)(ws + S_OFFS);
    float* mw    = (float*)(ws + S_MW);
    float* invmw = (float*)(ws + S_INVMW);
    float* part  = (float*)(ws + S_PART);
    int*   topi  = (int*)(ws + S_TOPI);
    float* topp  = (float*)(ws + S_TOPP);
    int*   stok  = (int*)(ws + S_STOK);
    int*   sexp  = (int*)(ws + S_SEXP);
    float* sw    = (float*)(ws + S_SW);
    float* isa   = (float*)(ws + S_ISA);
    float* isb   = (float*)(ws + S_ISB);

    hipMemsetAsync(d_out, 0, (size_t)out_size * sizeof(float), stream);
    hipMemsetAsync(ws + OFF_S, 0, 768, stream);  // cnt, fill, psum

    router_kernel<<<NTOK, 64, 0, stream>>>(x, rw, topi, topp, cnt, psum);
    kwsum_kernel<<<1024, 256, 0, stream>>>(w1, w2, part);
    kwscale_kernel<<<1, 64, 0, stream>>>(part, mw, invmw);
    kwquant_kernel<<<131072, 256, 0, stream>>>(w1, w2, invmw, w1q, w2q);
    kpfx_kernel<<<1, 1, 0, stream>>>(cnt, psum, offs, out + (out_size - 1));
    kfill_kernel<<<16, 256, 0, stream>>>(topi, topp, offs, fill, stok, sexp, sw);
    kaq_kernel<<<NPAIR, 64, 0, stream>>>(x, g1, stok, sexp, aq, isa);
    gemm1_kernel<<<dim3(32, 32, 16), 256, 0, stream>>>(aq, w1q, cnt, offs, isa, mw, h);
    khq_kernel<<<NPAIR, 256, 0, stream>>>(h, g2, sexp, hq, isb);
    gemm2_kernel<<<dim3(8, 32, 16), 256, 0, stream>>>(hq, w2q, cnt, offs, isb, sw, stok, mw, out);
}

// Round 2
// 1166.652 us; speedup vs baseline: 1.6176x; 1.6176x over previous
//
#include <hip/hip_runtime.h>
#include <hip/hip_bf16.h>
#include <math.h>

typedef __bf16 bf16;
typedef __attribute__((ext_vector_type(4))) __bf16 bf16x4;
typedef __attribute__((ext_vector_type(8))) __bf16 bf16x8;
typedef __attribute__((ext_vector_type(4))) float floatx4;

#define NTOK 4096
#define DM 1024
#define DF 4096
#define NE 16
#define NPAIR 8192

// ---------------- ws layout (bytes) ----------------
static const size_t OFF_W1Q = 0ull;                     // bf16 [16][4096][1024]  134217728
static const size_t OFF_W2Q = 134217728ull;             // bf16 [16][1024][4096]  134217728
static const size_t OFF_AQ  = 268435456ull;             // bf16 [8192+128][1024]   17039360
static const size_t OFF_HQ  = 285474816ull;             // bf16 [8192+128][4096]   68157440
static const size_t OFF_H   = 353632256ull;             // f32  [8192][4096]      134217728
static const size_t OFF_S   = 487849984ull;             // small arrays
static const size_t S_CNT   = OFF_S + 0;       // 16 i32
static const size_t S_OFFS  = OFF_S + 768;     // 17 i32
static const size_t S_MW    = OFF_S + 1024;    // 32 f32 (0..15 w1, 16..31 w2)
static const size_t S_INVMW = OFF_S + 1280;    // 32 f32
static const size_t S_PART  = OFF_S + 1536;    // 1024 f32
static const size_t S_TOPI  = OFF_S + 8192;    // 4096*2 i32
static const size_t S_TOPP  = OFF_S + 40960;   // 4096*2 f32
static const size_t S_STOK  = OFF_S + 73728;   // 8192 i32
static const size_t S_SEXP  = OFF_S + 106496;  // 8192 i32
static const size_t S_SW    = OFF_S + 139264;  // 8192 f32
static const size_t S_ISA   = OFF_S + 172032;  // 8192 f32
static const size_t S_ISB   = OFF_S + 204800;  // 8192 f32
static const size_t S_PROBS = OFF_S + 237568;  // 4096*16 f32 = 262144
static const size_t WS_REQUIRED = OFF_S + 237568ull + 262144ull;

// ---------------- helpers ----------------
__device__ __forceinline__ float wave_sum(float v) {
#pragma unroll
    for (int o = 32; o; o >>= 1) v += __shfl_xor(v, o, 64);
    return v;
}
__device__ __forceinline__ float wave_max(float v) {
#pragma unroll
    for (int o = 32; o; o >>= 1) v = fmaxf(v, __shfl_xor(v, o, 64));
    return v;
}
__device__ __forceinline__ float gelu_tanh(float v) {
    float u = 0.7978845608028654f * (v + 0.044715f * v * v * v);
    return 0.5f * v * (1.0f + tanhf(u));
}

__global__ void ksentinel(float* out) { out[0] = 1.0e30f; }  // ws too small marker

// ---------------- router: logits, softmax, top2; NO atomics ----------------
__global__ __launch_bounds__(64) void router_kernel(
    const float* __restrict__ x, const float* __restrict__ rw,
    int* __restrict__ topi, float* __restrict__ topp, float* __restrict__ probs)
{
    const int n = blockIdx.x;
    const int lane = threadIdx.x;
    const float* xr = x + (size_t)n * DM;
    float acc[16];
#pragma unroll
    for (int e = 0; e < 16; e++) acc[e] = 0.f;
    for (int i = 0; i < 16; i++) {
        const float xv = xr[i * 64 + lane];
#pragma unroll
        for (int e = 0; e < 16; e++) acc[e] += xv * rw[e * DM + i * 64 + lane];
    }
#pragma unroll
    for (int e = 0; e < 16; e++) acc[e] = wave_sum(acc[e]);  // replicated to all lanes
    float mx = acc[0];
#pragma unroll
    for (int e = 1; e < 16; e++) mx = fmaxf(mx, acc[e]);
    float p[16]; float den = 0.f;
#pragma unroll
    for (int e = 0; e < 16; e++) { p[e] = expf(acc[e] - mx); den += p[e]; }
    const float invden = 1.0f / den;
#pragma unroll
    for (int e = 0; e < 16; e++) p[e] *= invden;
    // coalesced probs write: lane e stores p[e]
    float myp = 0.f;
#pragma unroll
    for (int e = 0; e < 16; e++) myp = (lane == e) ? p[e] : myp;
    if (lane < 16) probs[n * 16 + lane] = myp;
    // top-2, earliest index wins ties (matches lax.top_k)
    if (lane == 0) {
        float b0 = -1.f; int i0 = 0;
#pragma unroll
        for (int e = 0; e < 16; e++) { if (p[e] > b0) { b0 = p[e]; i0 = e; } }
        float b1 = -1.f; int i1 = 0;
#pragma unroll
        for (int e = 0; e < 16; e++) { if (e != i0 && p[e] > b1) { b1 = p[e]; i1 = e; } }
        const float s = b0 + b1 + 1e-8f;
        topi[2 * n] = i0; topi[2 * n + 1] = i1;
        topp[2 * n] = b0 / s; topp[2 * n + 1] = b1 / s;
    }
}

// ---------------- single-block: histogram + psum reduce + offsets + aux ----------------
__global__ __launch_bounds__(256) void kreduce_kernel(
    const int* __restrict__ topi, const float* __restrict__ probs,
    int* __restrict__ cnt, int* __restrict__ offs, float* __restrict__ aux_out)
{
    const int tid = threadIdx.x;
    __shared__ int c16[16];
    __shared__ float pp[16][17];
    __shared__ float ps[16];
    if (tid < 16) c16[tid] = 0;
    __syncthreads();
    for (int idx = tid; idx < 2 * NTOK; idx += 256) atomicAdd(&c16[topi[idx]], 1);
    // psum: thread (g = tid>>4, e = tid&15) sums rows g, g+16, ...
    const int g = tid >> 4, e = tid & 15;
    float s = 0.f;
    for (int r = g; r < NTOK; r += 16) s += probs[r * 16 + e];
    pp[g][e] = s;
    __syncthreads();
    if (tid < 16) {
        float t = 0.f;
        for (int k = 0; k < 16; k++) t += pp[k][tid];
        ps[tid] = t;
        cnt[tid] = c16[tid];
    }
    __syncthreads();
    if (tid == 0) {
        int o = 0; float aux = 0.f;
        for (int k = 0; k < 16; k++) {
            offs[k] = o; o += c16[k];
            aux += ((float)c16[k] * (1.0f / 8192.0f)) * (ps[k] * (1.0f / 4096.0f));
        }
        offs[16] = o;
        *aux_out = 16.0f * aux;
    }
}

// ---------------- compaction: one block per expert, ballot prefix, no atomics ----------------
__global__ __launch_bounds__(256) void kfill_kernel(
    const int* __restrict__ topi, const float* __restrict__ topp,
    const int* __restrict__ offs,
    int* __restrict__ stok, int* __restrict__ sexp, float* __restrict__ sw)
{
    const int e = blockIdx.x;
    const int tid = threadIdx.x;
    const int wave = tid >> 6, lane = tid & 63;
    __shared__ int wcnt[4];
    int base = offs[e];
    for (int chunk = 0; chunk < 2 * NTOK; chunk += 256) {
        const int idx = chunk + tid;
        const int ti = topi[idx];
        const bool m = (ti == e);
        const unsigned long long mask = __ballot(m);
        const int wc = __popcll(mask);
        const int prefix = __popcll(mask & ((1ull << lane) - 1ull));
        if (lane == 0) wcnt[wave] = wc;
        __syncthreads();
        int woff = 0;
#pragma unroll
        for (int w = 0; w < 4; w++) woff += (w < wave) ? wcnt[w] : 0;
        const int tot = wcnt[0] + wcnt[1] + wcnt[2] + wcnt[3];
        if (m) {
            const int slot = base + woff + prefix;
            stok[slot] = idx >> 1; sexp[slot] = e; sw[slot] = topp[idx];
        }
        base += tot;
        __syncthreads();
    }
}

// ---------------- weight mean|w| partial reduce ----------------
__global__ __launch_bounds__(256) void kwsum_kernel(
    const float* __restrict__ w1, const float* __restrict__ w2, float* __restrict__ partial)
{
    const int b = blockIdx.x;                 // 1024 blocks: mat(1b) | e(4b) | chunk(5b)
    const int mat = b >> 9, e = (b >> 5) & 15, chunk = b & 31;
    const float4* w4 = (const float4*)((mat ? w2 : w1) + (size_t)e * 4194304ull + (size_t)chunk * 131072ull);
    const int tid = threadIdx.x;
    float s = 0.f;
    for (int i = 0; i < 128; i++) {
        float4 v = w4[i * 256 + tid];
        s += fabsf(v.x) + fabsf(v.y) + fabsf(v.z) + fabsf(v.w);
    }
    s = wave_sum(s);
    __shared__ float red[4];
    if ((tid & 63) == 0) red[tid >> 6] = s;
    __syncthreads();
    if (tid == 0) partial[b] = red[0] + red[1] + red[2] + red[3];
}

__global__ void kwscale_kernel(const float* __restrict__ partial,
                               float* __restrict__ mw, float* __restrict__ inv_mw)
{
    const int me = threadIdx.x;
    if (me < 32) {
        float s = 0.f;
        for (int c = 0; c < 32; c++) s += partial[me * 32 + c];
        const float mean = s * (1.0f / 4194304.0f);
        const float cm = fmaxf(mean, 1e-5f);
        mw[me] = cm;
        inv_mw[me] = 1.0f / cm;
    }
}

// ---------------- ternarize weights -> bf16 ----------------
__global__ __launch_bounds__(256) void kwquant_kernel(
    const float* __restrict__ w1, const float* __restrict__ w2,
    const float* __restrict__ inv_mw, bf16* __restrict__ w1q, bf16* __restrict__ w2q)
{
    const long long i = (long long)blockIdx.x * 256 + threadIdx.x;  // float4 index
    const int mat = i >= 16777216ll;
    const long long j = mat ? i - 16777216ll : i;
    const int e = (int)(j >> 20);
    const float inv = inv_mw[mat * 16 + e];
    const float4 v = ((const float4*)(mat ? w2 : w1))[j];
    bf16x4 q;
    q.x = (bf16)fminf(fmaxf(rintf(v.x * inv), -1.f), 1.f);
    q.y = (bf16)fminf(fmaxf(rintf(v.y * inv), -1.f), 1.f);
    q.z = (bf16)fminf(fmaxf(rintf(v.z * inv), -1.f), 1.f);
    q.w = (bf16)fminf(fmaxf(rintf(v.w * inv), -1.f), 1.f);
    ((bf16x4*)(mat ? w2q : w1q))[j] = q;
}

// ---------------- per-pair rmsnorm + act quant (x -> aq) ----------------
__global__ __launch_bounds__(64) void kaq_kernel(
    const float* __restrict__ x, const float* __restrict__ g1,
    const int* __restrict__ stok, const int* __restrict__ sexp,
    bf16* __restrict__ aq, float* __restrict__ inv_sa)
{
    const int slot = blockIdx.x;
    const int lane = threadIdx.x;
    const int tok = stok[slot], e = sexp[slot];
    const float4* xr = (const float4*)(x + (size_t)tok * DM);
    const float4* gr = (const float4*)(g1 + (size_t)e * DM);
    float4 xv[4]; float ss = 0.f;
#pragma unroll
    for (int i = 0; i < 4; i++) {
        xv[i] = xr[i * 64 + lane];
        ss += xv[i].x * xv[i].x + xv[i].y * xv[i].y + xv[i].z * xv[i].z + xv[i].w * xv[i].w;
    }
    ss = wave_sum(ss);
    const float rsq = rsqrtf(ss * (1.0f / DM) + 1e-6f);
    float4 xn[4]; float am = 0.f;
#pragma unroll
    for (int i = 0; i < 4; i++) {
        float4 g = gr[i * 64 + lane];
        xn[i].x = xv[i].x * g.x * rsq; xn[i].y = xv[i].y * g.y * rsq;
        xn[i].z = xv[i].z * g.z * rsq; xn[i].w = xv[i].w * g.w * rsq;
        am = fmaxf(am, fmaxf(fmaxf(fabsf(xn[i].x), fabsf(xn[i].y)),
                             fmaxf(fabsf(xn[i].z), fabsf(xn[i].w))));
    }
    am = wave_max(am);
    const float cm = fmaxf(am, 1e-5f);
    const float sc = 127.0f / cm;
    bf16x4* ar = (bf16x4*)(aq + (size_t)slot * DM);
#pragma unroll
    for (int i = 0; i < 4; i++) {
        bf16x4 q;
        q.x = (bf16)fminf(fmaxf(rintf(xn[i].x * sc), -128.f), 127.f);
        q.y = (bf16)fminf(fmaxf(rintf(xn[i].y * sc), -128.f), 127.f);
        q.z = (bf16)fminf(fmaxf(rintf(xn[i].z * sc), -128.f), 127.f);
        q.w = (bf16)fminf(fmaxf(rintf(xn[i].w * sc), -128.f), 127.f);
        ar[i * 64 + lane] = q;
    }
    if (lane == 0) inv_sa[slot] = cm / 127.0f;
}

// ---------------- h rmsnorm + act quant (h -> hq) ----------------
__global__ __launch_bounds__(256) void khq_kernel(
    const float* __restrict__ h, const float* __restrict__ g2,
    const int* __restrict__ sexp, bf16* __restrict__ hq, float* __restrict__ inv_sb)
{
    const int slot = blockIdx.x;
    const int tid = threadIdx.x;
    const int wave = tid >> 6, lane = tid & 63;
    const int e = sexp[slot];
    const float4* hr = (const float4*)(h + (size_t)slot * DF);
    const float4* gr = (const float4*)(g2 + (size_t)e * DF);
    __shared__ float red[4];
    float4 hv[4]; float ss = 0.f;
#pragma unroll
    for (int i = 0; i < 4; i++) {
        hv[i] = hr[i * 256 + tid];
        ss += hv[i].x * hv[i].x + hv[i].y * hv[i].y + hv[i].z * hv[i].z + hv[i].w * hv[i].w;
    }
    ss = wave_sum(ss);
    if (lane == 0) red[wave] = ss;
    __syncthreads();
    ss = red[0] + red[1] + red[2] + red[3];
    const float rsq = rsqrtf(ss * (1.0f / DF) + 1e-6f);
    float4 tn[4]; float am = 0.f;
#pragma unroll
    for (int i = 0; i < 4; i++) {
        float4 g = gr[i * 256 + tid];
        tn[i].x = hv[i].x * g.x * rsq; tn[i].y = hv[i].y * g.y * rsq;
        tn[i].z = hv[i].z * g.z * rsq; tn[i].w = hv[i].w * g.w * rsq;
        am = fmaxf(am, fmaxf(fmaxf(fabsf(tn[i].x), fabsf(tn[i].y)),
                             fmaxf(fabsf(tn[i].z), fabsf(tn[i].w))));
    }
    am = wave_max(am);
    __syncthreads();
    if (lane == 0) red[wave] = am;
    __syncthreads();
    am = fmaxf(fmaxf(red[0], red[1]), fmaxf(red[2], red[3]));
    const float cm = fmaxf(am, 1e-5f);
    const float sc = 127.0f / cm;
    bf16x4* orow = (bf16x4*)(hq + (size_t)slot * DF);
#pragma unroll
    for (int i = 0; i < 4; i++) {
        bf16x4 q;
        q.x = (bf16)fminf(fmaxf(rintf(tn[i].x * sc), -128.f), 127.f);
        q.y = (bf16)fminf(fmaxf(rintf(tn[i].y * sc), -128.f), 127.f);
        q.z = (bf16)fminf(fmaxf(rintf(tn[i].z * sc), -128.f), 127.f);
        q.w = (bf16)fminf(fmaxf(rintf(tn[i].w * sc), -128.f), 127.f);
        orow[i * 256 + tid] = q;
    }
    if (tid == 0) inv_sb[slot] = cm / 127.0f;
}

// ---------------- MFMA mainloop: 128x128 tile, BK=64, 4 waves of 64x64 ----------------
__device__ __forceinline__ void gemm_mainloop(
    const bf16* __restrict__ Ab, const bf16* __restrict__ Bb,
    const int kdim, bf16* As, bf16* Bs, floatx4 acc[4][4])
{
    const int tid = threadIdx.x;
    const int wave = tid >> 6, lane = tid & 63;
    const int wr = (wave >> 1) * 64, wc = (wave & 1) * 64;
    const int quad = lane >> 4, l16 = lane & 15;
    const int sr = tid >> 1, sh = (tid & 1) * 32;
    const float4* gA = (const float4*)(Ab + (size_t)sr * kdim + sh);
    const float4* gB = (const float4*)(Bb + (size_t)sr * kdim + sh);
    float4* lA = (float4*)(As + sr * 72 + sh);
    float4* lB = (float4*)(Bs + sr * 72 + sh);
    const int kIters = kdim >> 6;
    for (int ki = 0; ki < kIters; ++ki) {
        __syncthreads();
        float4 a0 = gA[0], a1 = gA[1], a2 = gA[2], a3 = gA[3];
        float4 b0 = gB[0], b1 = gB[1], b2 = gB[2], b3 = gB[3];
        gA += 8; gB += 8;
        lA[0] = a0; lA[1] = a1; lA[2] = a2; lA[3] = a3;
        lB[0] = b0; lB[1] = b1; lB[2] = b2; lB[3] = b3;
        __syncthreads();
#pragma unroll
        for (int kk = 0; kk < 64; kk += 32) {
            bf16x8 af[4], bfm[4];
#pragma unroll
            for (int i = 0; i < 4; i++)
                af[i] = *(const bf16x8*)(As + (wr + 16 * i + l16) * 72 + kk + quad * 8);
#pragma unroll
            for (int j = 0; j < 4; j++)
                bfm[j] = *(const bf16x8*)(Bs + (wc + 16 * j + l16) * 72 + kk + quad * 8);
#pragma unroll
            for (int i = 0; i < 4; i++)
#pragma unroll
                for (int j = 0; j < 4; j++)
                    acc[i][j] = __builtin_amdgcn_mfma_f32_16x16x32_bf16(af[i], bfm[j], acc[i][j], 0, 0, 0);
        }
    }
}

// ---------------- GEMM1: h = gelu(scale * (aq @ w1q^T)) ----------------
__global__ __launch_bounds__(256) void gemm1_kernel(
    const bf16* __restrict__ aq, const bf16* __restrict__ w1q,
    const int* __restrict__ cnt, const int* __restrict__ offs,
    const float* __restrict__ inv_sa, const float* __restrict__ mw,
    float* __restrict__ h)
{
    const int e = blockIdx.z;
    const int ce = cnt[e];
    const int m0 = blockIdx.y * 128;
    if (m0 >= ce) return;
    const int n0 = blockIdx.x * 128;
    const int off = offs[e];
    __shared__ bf16 As[128 * 72];
    __shared__ bf16 Bs[128 * 72];
    floatx4 acc[4][4];
#pragma unroll
    for (int i = 0; i < 4; i++)
#pragma unroll
        for (int j = 0; j < 4; j++) { floatx4 z = {0.f, 0.f, 0.f, 0.f}; acc[i][j] = z; }
    gemm_mainloop(aq + (size_t)(off + m0) * DM, w1q + ((size_t)e * DF + n0) * DM, DM, As, Bs, acc);
    const int tid = threadIdx.x, wave = tid >> 6, lane = tid & 63;
    const int wr = (wave >> 1) * 64, wc = (wave & 1) * 64, quad = lane >> 4, l16 = lane & 15;
    const float sm = mw[e];
#pragma unroll
    for (int i = 0; i < 4; i++) {
#pragma unroll
        for (int r = 0; r < 4; r++) {
            const int ml = wr + 16 * i + quad * 4 + r;
            if (m0 + ml < ce) {
                const int slot = off + m0 + ml;
                const float sc = sm * inv_sa[slot];
                float* hrow = h + (size_t)slot * DF + n0 + wc + l16;
#pragma unroll
                for (int j = 0; j < 4; j++) hrow[16 * j] = gelu_tanh(acc[i][j][r] * sc);
            }
        }
    }
}

// ---------------- GEMM2: out += w_pair * scale * (hq @ w2q^T), atomic scatter ----------------
__global__ __launch_bounds__(256) void gemm2_kernel(
    const bf16* __restrict__ hq, const bf16* __restrict__ w2q,
    const int* __restrict__ cnt, const int* __restrict__ offs,
    const float* __restrict__ inv_sb, const float* __restrict__ sw,
    const int* __restrict__ stok, const float* __restrict__ mw,
    float* __restrict__ out)
{
    const int e = blockIdx.z;
    const int ce = cnt[e];
    const int m0 = blockIdx.y * 128;
    if (m0 >= ce) return;
    const int n0 = blockIdx.x * 128;
    const int off = offs[e];
    __shared__ bf16 As[128 * 72];
    __shared__ bf16 Bs[128 * 72];
    floatx4 acc[4][4];
#pragma unroll
    for (int i = 0; i < 4; i++)
#pragma unroll
        for (int j = 0; j < 4; j++) { floatx4 z = {0.f, 0.f, 0.f, 0.f}; acc[i][j] = z; }
    gemm_mainloop(hq + (size_t)(off + m0) * DF, w2q + ((size_t)e * DM + n0) * DF, DF, As, Bs, acc);
    const int tid = threadIdx.x, wave = tid >> 6, lane = tid & 63;
    const int wr = (wave >> 1) * 64, wc = (wave & 1) * 64, quad = lane >> 4, l16 = lane & 15;
    const float sm = mw[16 + e];
#pragma unroll
    for (int i = 0; i < 4; i++) {
#pragma unroll
        for (int r = 0; r < 4; r++) {
            const int ml = wr + 16 * i + quad * 4 + r;
            if (m0 + ml < ce) {
                const int slot = off + m0 + ml;
                const float sc = sm * inv_sb[slot] * sw[slot];
                const int tok = stok[slot];
                float* orow = out + (size_t)tok * DM + n0 + wc + l16;
#pragma unroll
                for (int j = 0; j < 4; j++) atomicAdd(&orow[16 * j], acc[i][j][r] * sc);
            }
        }
    }
}

// ---------------- launcher ----------------
extern "C" void kernel_launch(void* const* d_in, const int* in_sizes, int n_in,
                              void* d_out, int out_size, void* d_ws, size_t ws_size,
                              hipStream_t stream)
{
    const float* x  = (const float*)d_in[0];
    const float* rw = (const float*)d_in[1];
    const float* w1 = (const float*)d_in[2];
    const float* g1 = (const float*)d_in[3];
    const float* w2 = (const float*)d_in[4];
    const float* g2 = (const float*)d_in[5];
    float* out = (float*)d_out;
    char* ws = (char*)d_ws;

    if (ws_size < WS_REQUIRED) {
        ksentinel<<<1, 1, 0, stream>>>(out);
        return;
    }

    bf16*  w1q   = (bf16*)(ws + OFF_W1Q);
    bf16*  w2q   = (bf16*)(ws + OFF_W2Q);
    bf16*  aq    = (bf16*)(ws + OFF_AQ);
    bf16*  hq    = (bf16*)(ws + OFF_HQ);
    float* h     = (float*)(ws + OFF_H);
    int*   cnt   = (int*)(ws + S_CNT);
    int*   offs  = (int*)(ws + S_OFFS);
    float* mw    = (float*)(ws + S_MW);
    float* invmw = (float*)(ws + S_INVMW);
    float* part  = (float*)(ws + S_PART);
    int*   topi  = (int*)(ws + S_TOPI);
    float* topp  = (float*)(ws + S_TOPP);
    int*   stok  = (int*)(ws + S_STOK);
    int*   sexp  = (int*)(ws + S_SEXP);
    float* sw    = (float*)(ws + S_SW);
    float* isa   = (float*)(ws + S_ISA);
    float* isb   = (float*)(ws + S_ISB);
    float* probs = (float*)(ws + S_PROBS);

    hipMemsetAsync(d_out, 0, (size_t)out_size * sizeof(float), stream);

    router_kernel<<<NTOK, 64, 0, stream>>>(x, rw, topi, topp, probs);
    kwsum_kernel<<<1024, 256, 0, stream>>>(w1, w2, part);
    kwscale_kernel<<<1, 64, 0, stream>>>(part, mw, invmw);
    kwquant_kernel<<<131072, 256, 0, stream>>>(w1, w2, invmw, w1q, w2q);
    kreduce_kernel<<<1, 256, 0, stream>>>(topi, probs, cnt, offs, out + (out_size - 1));
    kfill_kernel<<<16, 256, 0, stream>>>(topi, topp, offs, stok, sexp, sw);
    kaq_kernel<<<NPAIR, 64, 0, stream>>>(x, g1, stok, sexp, aq, isa);
    gemm1_kernel<<<dim3(32, 32, 16), 256, 0, stream>>>(aq, w1q, cnt, offs, isa, mw, h);
    khq_kernel<<<NPAIR, 256, 0, stream>>>(h, g2, sexp, hq, isb);
    gemm2_kernel<<<dim3(8, 32, 16), 256, 0, stream>>>(hq, w2q, cnt, offs, isb, sw, stok, mw, out);
}